// Round 2
// baseline (948.988 us; speedup 1.0000x reference)
//
#include <hip/hip_runtime.h>

// LRU linear scan h_t = a*h_{t-1} + b*x_t, single-pass decoupled lookback.
// a = exp(-exp(W)), b = sqrt(1-(a-1)^2) per channel.
// Linearity: with chunk-local scan l_i (from h=0) and incoming carry C:
//   h_i = l_i + a^(i+1) * C.  Chunk aggregate E = l_{L-1}; prefix P = E + a^L * C.

#define BB 16
#define TT 4096
#define DD 512
#define LL 16            // timesteps per tile (held in registers: 16 float4/thread)
#define KK (TT / LL)     // 256 tiles along T per batch
#define NT (BB * KK)     // 4096 tiles total
#define D4 (DD / 4)      // 128 float4 lanes across D

#define WS_FLAGS_OFF 1024                    // bytes; counter at 0
#define WS_E_OFF     32768                   // bytes
#define WS_P_OFF     (WS_E_OFF + NT * DD * 4)

__device__ __forceinline__ float aload(const float* p) {
    return __hip_atomic_load(p, __ATOMIC_RELAXED, __HIP_MEMORY_SCOPE_AGENT);
}
__device__ __forceinline__ void astore(float* p, float v) {
    __hip_atomic_store(p, v, __ATOMIC_RELAXED, __HIP_MEMORY_SCOPE_AGENT);
}

__global__ __launch_bounds__(256) void lru_init(int* ws) {
    int i = blockIdx.x * blockDim.x + threadIdx.x;
    if (i < WS_E_OFF / 4) ws[i] = 0;   // zero counter + flags region
}

__global__ __launch_bounds__(D4) void lru_scan(const float4* __restrict__ x,
                                               const float* __restrict__ W,
                                               float4* __restrict__ out,
                                               int* __restrict__ counter,
                                               int* __restrict__ flags,
                                               float* __restrict__ E,
                                               float* __restrict__ P) {
    __shared__ int s_tile;
    __shared__ int s_flag;
    const int tid = threadIdx.x;
    if (tid == 0) s_tile = atomicAdd(counter, 1);
    __syncthreads();
    const int tile = s_tile;
    const int b = tile & (BB - 1);
    const int k = tile >> 4;           // BB == 16
    const int d = tid * 4;

    // per-channel coefficients
    float e, w;
    e = expf(-expf(W[d + 0])); const float a0 = e; w = e - 1.0f; const float bb0 = sqrtf(1.0f - w * w);
    e = expf(-expf(W[d + 1])); const float a1 = e; w = e - 1.0f; const float bb1 = sqrtf(1.0f - w * w);
    e = expf(-expf(W[d + 2])); const float a2 = e; w = e - 1.0f; const float bb2 = sqrtf(1.0f - w * w);
    e = expf(-expf(W[d + 3])); const float a3 = e; w = e - 1.0f; const float bb3 = sqrtf(1.0f - w * w);
    // aL = a^LL (LL=16 -> 4 squarings)
    float aL0 = a0, aL1 = a1, aL2 = a2, aL3 = a3;
#pragma unroll
    for (int s = 0; s < 4; ++s) { aL0 *= aL0; aL1 *= aL1; aL2 *= aL2; aL3 *= aL3; }

    // chunk-local scan from 0; keep all L states in registers
    const size_t base = ((size_t)b * TT + (size_t)k * LL) * D4 + tid;
    float4 h[LL];
    float h0 = 0.f, h1 = 0.f, h2 = 0.f, h3 = 0.f;
#pragma unroll
    for (int i = 0; i < LL; ++i) {
        float4 v = x[base + (size_t)i * D4];
        h0 = a0 * h0 + bb0 * v.x;
        h1 = a1 * h1 + bb1 * v.y;
        h2 = a2 * h2 + bb2 * v.z;
        h3 = a3 * h3 + bb3 * v.w;
        h[i] = make_float4(h0, h1, h2, h3);
    }

    float c0 = 0.f, c1 = 0.f, c2 = 0.f, c3 = 0.f;
    float* Erow = E + (size_t)tile * DD + d;
    float* Prow = P + (size_t)tile * DD + d;

    if (k == 0) {
        // prefix == aggregate; publish flag=2 directly
        astore(Prow + 0, h0); astore(Prow + 1, h1);
        astore(Prow + 2, h2); astore(Prow + 3, h3);
        __syncthreads();   // drains vmcnt before barrier -> payload visible
        if (tid == 0)
            __hip_atomic_store(&flags[tile], 2, __ATOMIC_RELEASE, __HIP_MEMORY_SCOPE_AGENT);
    } else {
        // publish aggregate
        astore(Erow + 0, h0); astore(Erow + 1, h1);
        astore(Erow + 2, h2); astore(Erow + 3, h3);
        __syncthreads();
        if (tid == 0)
            __hip_atomic_store(&flags[tile], 1, __ATOMIC_RELEASE, __HIP_MEMORY_SCOPE_AGENT);

        // lookback: C = sum_j a^(L*(k-1-j)) * E_j, terminated by a PREFIX tile
        float s0 = 1.f, s1 = 1.f, s2 = 1.f, s3 = 1.f;
        for (int j = k - 1; j >= 0; --j) {
            const int jt = (j << 4) | b;
            if (tid == 0) {
                int f;
                for (;;) {
                    f = __hip_atomic_load(&flags[jt], __ATOMIC_ACQUIRE, __HIP_MEMORY_SCOPE_AGENT);
                    if (f != 0) break;
                    __builtin_amdgcn_s_sleep(1);
                }
                s_flag = f;
            }
            __syncthreads();
            const int f = s_flag;
            __syncthreads();
            const float* src = (f == 2) ? (P + (size_t)jt * DD + d)
                                        : (E + (size_t)jt * DD + d);
            float v0 = aload(src + 0), v1 = aload(src + 1);
            float v2 = aload(src + 2), v3 = aload(src + 3);
            c0 += s0 * v0; c1 += s1 * v1; c2 += s2 * v2; c3 += s3 * v3;
            if (f == 2) break;
            s0 *= aL0; s1 *= aL1; s2 *= aL2; s3 *= aL3;
        }

        // publish inclusive prefix P = E + a^L * C
        astore(Prow + 0, h0 + aL0 * c0);
        astore(Prow + 1, h1 + aL1 * c1);
        astore(Prow + 2, h2 + aL2 * c2);
        astore(Prow + 3, h3 + aL3 * c3);
        __syncthreads();
        if (tid == 0)
            __hip_atomic_store(&flags[tile], 2, __ATOMIC_RELEASE, __HIP_MEMORY_SCOPE_AGENT);
    }

    // write out: out_i = l_i + a^(i+1) * C
    float s0 = a0, s1 = a1, s2 = a2, s3 = a3;
#pragma unroll
    for (int i = 0; i < LL; ++i) {
        float4 o = h[i];
        o.x += s0 * c0; o.y += s1 * c1; o.z += s2 * c2; o.w += s3 * c3;
        out[base + (size_t)i * D4] = o;
        s0 *= a0; s1 *= a1; s2 *= a2; s3 *= a3;
    }
}

extern "C" void kernel_launch(void* const* d_in, const int* in_sizes, int n_in,
                              void* d_out, int out_size, void* d_ws, size_t ws_size,
                              hipStream_t stream) {
    const float4* x = (const float4*)d_in[0];   // [B,T,D] fp32
    const float*  W = (const float*)d_in[1];    // [D] fp32
    float4* out = (float4*)d_out;

    char* ws = (char*)d_ws;
    int*   counter = (int*)ws;                      // @0
    int*   flags   = (int*)(ws + WS_FLAGS_OFF);     // NT ints
    float* E       = (float*)(ws + WS_E_OFF);       // NT x DD
    float* P       = (float*)(ws + WS_P_OFF);       // NT x DD

    lru_init<<<dim3(WS_E_OFF / 4 / 256), dim3(256), 0, stream>>>((int*)ws);
    lru_scan<<<dim3(NT), dim3(D4), 0, stream>>>(x, W, out, counter, flags, E, P);
}

// Round 4
// 259.609 us; speedup vs baseline: 3.6554x; 3.6554x over previous
//
#include <hip/hip_runtime.h>

// LRU linear scan: h_t = a*h_{t-1} + b*x_t, output full sequence [B,T,D] fp32.
// a = exp(-exp(W)), b = sqrt(1-(a-1)^2) per channel.
// 3-phase chunked scan: chunk-ends -> carries (separate in/out bufs!) -> rescan.

#define BB 16
#define TT 4096
#define DD 512
#define KK 128         // chunks along T
#define LL (TT / KK)   // 32 steps per chunk
#define D4 (DD / 4)    // 128 float4 lanes across D

typedef float vfloat4 __attribute__((ext_vector_type(4)));  // native vec for nt-store

__device__ __forceinline__ void coeffs(const float* __restrict__ W, int d,
                                       float& a0, float& a1, float& a2, float& a3,
                                       float& b0, float& b1, float& b2, float& b3) {
    float e, w;
    e = expf(-expf(W[d + 0])); a0 = e; w = e - 1.0f; b0 = sqrtf(1.0f - w * w);
    e = expf(-expf(W[d + 1])); a1 = e; w = e - 1.0f; b1 = sqrtf(1.0f - w * w);
    e = expf(-expf(W[d + 2])); a2 = e; w = e - 1.0f; b2 = sqrtf(1.0f - w * w);
    e = expf(-expf(W[d + 3])); a3 = e; w = e - 1.0f; b3 = sqrtf(1.0f - w * w);
}

// Phase 1: per (b, k, d4) scan chunk from h=0, write chunk-end E[b,k,d4].
// block = (128, 2): ty selects chunk; 4 waves/block, 16 waves/CU.
__global__ __launch_bounds__(256) void lru_phase1(const float4* __restrict__ x,
                                                  const float* __restrict__ W,
                                                  float4* __restrict__ E) {
    const int d4 = threadIdx.x;                       // 0..127
    const int k  = blockIdx.x * 2 + threadIdx.y;      // 0..KK-1
    const int b  = blockIdx.y;                        // 0..BB-1
    const int d  = d4 * 4;

    float a0, a1, a2, a3, b0, b1, b2, b3;
    coeffs(W, d, a0, a1, a2, a3, b0, b1, b2, b3);

    const float4* xp = x + ((size_t)b * TT + (size_t)k * LL) * D4 + d4;
    float h0 = 0.f, h1 = 0.f, h2 = 0.f, h3 = 0.f;
#pragma unroll 8
    for (int i = 0; i < LL; ++i) {
        float4 v = xp[(size_t)i * D4];
        h0 = a0 * h0 + b0 * v.x;
        h1 = a1 * h1 + b1 * v.y;
        h2 = a2 * h2 + b2 * v.z;
        h3 = a3 * h3 + b3 * v.w;
    }
    E[((size_t)b * KK + k) * D4 + d4] = make_float4(h0, h1, h2, h3);
}

// Phase 2: E (chunk-ends) -> C (carry INTO each chunk). Separate restrict
// buffers so loads pipeline: C_0 = 0, C_k = aL*C_{k-1} + E_{k-1}.
__global__ __launch_bounds__(D4) void lru_phase2(const float* __restrict__ W,
                                                 const float4* __restrict__ E,
                                                 float4* __restrict__ C) {
    const int d4 = threadIdx.x;
    const int b  = blockIdx.x;
    const int d  = d4 * 4;

    float a0, a1, a2, a3, b0, b1, b2, b3;
    coeffs(W, d, a0, a1, a2, a3, b0, b1, b2, b3);

    // aL = a^LL (LL=32 -> 5 squarings)
    float aL0 = a0, aL1 = a1, aL2 = a2, aL3 = a3;
#pragma unroll
    for (int s = 0; s < 5; ++s) { aL0 *= aL0; aL1 *= aL1; aL2 *= aL2; aL3 *= aL3; }

    float c0 = 0.f, c1 = 0.f, c2 = 0.f, c3 = 0.f;
    const size_t row = (size_t)b * KK * D4 + d4;
#pragma unroll 8
    for (int k = 0; k < KK; ++k) {
        float4 e = E[row + (size_t)k * D4];
        C[row + (size_t)k * D4] = make_float4(c0, c1, c2, c3);
        c0 = aL0 * c0 + e.x;
        c1 = aL1 * c1 + e.y;
        c2 = aL2 * c2 + e.z;
        c3 = aL3 * c3 + e.w;
    }
}

// Phase 3: rescan each chunk starting from its carry; nontemporal out stores.
__global__ __launch_bounds__(256) void lru_phase3(const float4* __restrict__ x,
                                                  const float* __restrict__ W,
                                                  const float4* __restrict__ C,
                                                  float4* __restrict__ out) {
    const int d4 = threadIdx.x;
    const int k  = blockIdx.x * 2 + threadIdx.y;
    const int b  = blockIdx.y;
    const int d  = d4 * 4;

    float a0, a1, a2, a3, b0, b1, b2, b3;
    coeffs(W, d, a0, a1, a2, a3, b0, b1, b2, b3);

    float4 c = C[((size_t)b * KK + k) * D4 + d4];
    float h0 = c.x, h1 = c.y, h2 = c.z, h3 = c.w;

    const size_t base = ((size_t)b * TT + (size_t)k * LL) * D4 + d4;
    const float4* xp = x + base;
    vfloat4* op = (vfloat4*)(out + base);
#pragma unroll 8
    for (int i = 0; i < LL; ++i) {
        float4 v = xp[(size_t)i * D4];
        h0 = a0 * h0 + b0 * v.x;
        h1 = a1 * h1 + b1 * v.y;
        h2 = a2 * h2 + b2 * v.z;
        h3 = a3 * h3 + b3 * v.w;
        vfloat4 o; o.x = h0; o.y = h1; o.z = h2; o.w = h3;
        __builtin_nontemporal_store(o, &op[(size_t)i * D4]);
    }
}

extern "C" void kernel_launch(void* const* d_in, const int* in_sizes, int n_in,
                              void* d_out, int out_size, void* d_ws, size_t ws_size,
                              hipStream_t stream) {
    const float4* x = (const float4*)d_in[0];   // [B,T,D] fp32
    const float*  W = (const float*)d_in[1];    // [D] fp32
    float4* out = (float4*)d_out;               // [B,T,D] fp32

    char* ws = (char*)d_ws;
    float4* E = (float4*)ws;                              // [B,KK,D] = 4 MiB
    float4* C = (float4*)(ws + (size_t)BB * KK * DD * 4); // [B,KK,D] = 4 MiB

    dim3 grid(KK / 2, BB);
    dim3 block(D4, 2);
    lru_phase1<<<grid, block, 0, stream>>>(x, W, E);
    lru_phase2<<<dim3(BB), dim3(D4), 0, stream>>>(W, E, C);
    lru_phase3<<<grid, block, 0, stream>>>(x, W, C, out);
}